// Round 13
// baseline (402.473 us; speedup 1.0000x reference)
//
#include <hip/hip_runtime.h>
#include <stdint.h>

#define BB 4
#define LL 16384
#define CC 512
#define MM (BB * LL)  // 65536

typedef unsigned short u16;
typedef __bf16 bf16x8 __attribute__((ext_vector_type(8)));
typedef float f32x4 __attribute__((ext_vector_type(4)));
typedef u16 u16x8 __attribute__((ext_vector_type(8)));
typedef u16 u16x4 __attribute__((ext_vector_type(4)));

__device__ __forceinline__ u16 f2bf(float f) {
  return __builtin_bit_cast(u16, (__bf16)f);
}

__device__ __forceinline__ void gl_lds16(const void* g, void* l) {
  __builtin_amdgcn_global_load_lds((const __attribute__((address_space(1))) void*)g,
                                   (__attribute__((address_space(3))) void*)l,
                                   16, 0, 0);
}

// ------- weight transpose+convert via 64x64 LDS tiles: W[K][N] -> Wt[N][K] bf16 -------
__global__ __launch_bounds__(256) void tcvt_kernel(const float* __restrict__ Wq,
                                                   const float* __restrict__ Wkv,
                                                   const float* __restrict__ Wfc,
                                                   u16* __restrict__ Wq_t,
                                                   u16* __restrict__ Wkv_t,
                                                   u16* __restrict__ Wfc_t) {
  __shared__ float tile[64][65];
  const int bid = blockIdx.x, tid = threadIdx.x;
  const float* W; u16* Wt; int N, ti;
  if (bid < 64)       { W = Wq;  Wt = Wq_t;  N = 512;  ti = bid; }
  else if (bid < 192) { W = Wkv; Wt = Wkv_t; N = 1024; ti = bid - 64; }
  else                { W = Wfc; Wt = Wfc_t; N = 512;  ti = bid - 192; }
  const int ntn = N >> 6;
  const int kt = ti / ntn, nt = ti % ntn;
  const int k0 = kt << 6, n0 = nt << 6;
  {
    const int r = tid >> 4, c4 = tid & 15;
#pragma unroll
    for (int e = 0; e < 4; ++e) {
      int row = r + e * 16;
      f32x4 v = *reinterpret_cast<const f32x4*>(&W[(size_t)(k0 + row) * N + n0 + c4 * 4]);
      tile[row][c4 * 4 + 0] = v[0]; tile[row][c4 * 4 + 1] = v[1];
      tile[row][c4 * 4 + 2] = v[2]; tile[row][c4 * 4 + 3] = v[3];
    }
  }
  __syncthreads();
  {
    const int n = tid >> 2, qd = tid & 3;
#pragma unroll
    for (int e = 0; e < 2; ++e) {
      int c = qd * 2 + e;
      u16x8 o;
#pragma unroll
      for (int j = 0; j < 8; ++j) o[j] = f2bf(tile[c * 8 + j][n]);
      *reinterpret_cast<u16x8*>(&Wt[(size_t)(n0 + n) * 512 + k0 + c * 8]) = o;
    }
  }
}

// ---- 128x128 2-phase NT GEMM, 3 blocks/CU: C[M][N] = A[M][512] * Bt[N][512]^T ----
// 256 threads (4 waves, 2M x 2N, 64x64/wave). LDS 48KB: A double-buffer (2x16KB,
// bf16) + B single-buffer (16KB) -> 3 blocks/CU (co-resident blocks interleave
// DS/MFMA/stall phases).
//
// A_F32=false: A bf16, staged via global_load_lds (pre-swizzled source).
// A_F32=true: A fp32 in global, FUSED convert: p1 issues 8 dwordx4 reg-loads of
//   A(u+1); p2 after MFMA does vmcnt(4) -- the 4 B gl_lds issued this phase are
//   the ONLY younger ops, so this waits exactly the A reg-loads (issued a full
//   phase + MFMA earlier) -- then converts and ds_write_b128 into LAn. LAn's
//   readers closed at tile u-1's end barrier, so the write is race-free
//   anywhere in tile u. Own-wave lgkmcnt(0) + end-of-tile vmcnt(0)+barrier
//   publish the ds_writes and B(u+1) exactly as the bf16 path does.
// B single-buffered: all B ds_reads of tile u drained (each wave's lgkm(0))
// before p1's post-MFMA barrier -> stageB(u+1) @p2 is safe.
template <bool A_F32, bool OUT_F32>
__global__ __launch_bounds__(256, 3) void gemm128(const void* __restrict__ Ap,
                                                  const u16* __restrict__ Bt,
                                                  void* __restrict__ Cp,
                                                  int N, int nbnl) {
  constexpr int K = 512;
  constexpr int NT = 8;
  __shared__ __align__(16) u16 Al[2][8192];
  __shared__ __align__(16) u16 Bl[8192];
  const u16* A16 = (const u16*)Ap;
  const float* A32 = (const float*)Ap;
  const int nwg = gridDim.x;
  const int bid0 = blockIdx.x;
  const int cpx = nwg >> 3;  // grids are multiples of 8
  const int bid = (bid0 & 7) * cpx + (bid0 >> 3);
  const int bm = bid >> nbnl, bn = bid & ((1 << nbnl) - 1);
  const size_t row0 = (size_t)bm << 7, col0 = (size_t)bn << 7;
  const int tid = threadIdx.x, lane = tid & 63;
  const int wv = tid >> 6, wm = wv >> 1, wn = wv & 1;
  const int ro = lane & 15, g4 = lane >> 4;

  // staging: 1024 16B chunks per 128x64 bf16 tile; chunk cc = (row r = cc>>3,
  // colgroup g = cc&7). LDS dest LINEAR; global source pre-swizzled g^(r&7).
  auto stageA16 = [&](int kt, u16* L) {
#pragma unroll
    for (int c = 0; c < 4; ++c) {
      int cc = tid + c * 256;
      int r = cc >> 3, g = (cc & 7) ^ (r & 7);
      gl_lds16(A16 + (row0 + r) * (size_t)K + kt * 64 + g * 8, L + cc * 8);
    }
  };
  auto stageB = [&](int kt) {
#pragma unroll
    for (int c = 0; c < 4; ++c) {
      int cc = tid + c * 256;
      int r = cc >> 3, g = (cc & 7) ^ (r & 7);
      gl_lds16(Bt + (col0 + r) * (size_t)K + kt * 64 + g * 8, Bl + cc * 8);
    }
  };

  // fp32 A reg-staging: same chunk geometry, 2 dwordx4 per chunk, cvt on write.
  f32x4 av[4][2];
  auto aloadR = [&](int kt) {
#pragma unroll
    for (int c = 0; c < 4; ++c) {
      int cc = tid + c * 256;
      int r = cc >> 3, g = (cc & 7) ^ (r & 7);
      const float* s = A32 + (row0 + r) * (size_t)K + kt * 64 + g * 8;
      av[c][0] = *reinterpret_cast<const f32x4*>(s);
      av[c][1] = *reinterpret_cast<const f32x4*>(s + 4);
    }
  };
  auto awrite = [&](u16* L) {
#pragma unroll
    for (int c = 0; c < 4; ++c) {
      int cc = tid + c * 256;
      bf16x8 w;
#pragma unroll
      for (int e = 0; e < 8; ++e) w[e] = (__bf16)av[c][e >> 2][e & 3];
      *reinterpret_cast<bf16x8*>(L + cc * 8) = w;
    }
  };

  // ds_read offsets (u16 elems), swizzled: phys colgroup = logical ^ (row&7)
  const int aB = (wm * 64 + ro) * 64;
  const int bB = (wn * 64 + ro) * 64;
  const int sw0 = (g4 ^ (ro & 7)) * 8;
  const int sw1 = ((g4 + 4) ^ (ro & 7)) * 8;

  auto ldf = [&](const u16* p) { return *reinterpret_cast<const bf16x8*>(p); };

  f32x4 acc[4][4] = {};

  // prologue: stage tile 0, full drain
  if (A_F32) {
    aloadR(0); stageB(0);
    asm volatile("s_waitcnt vmcnt(4)" ::: "memory");  // A reg-loads done
    awrite(Al[0]);
    asm volatile("s_waitcnt vmcnt(0) lgkmcnt(0)" ::: "memory");
  } else {
    stageA16(0, Al[0]); stageB(0);
    asm volatile("s_waitcnt vmcnt(0)" ::: "memory");
  }
  __builtin_amdgcn_s_barrier();

  for (int u = 0; u < NT; ++u) {
    u16* LA = Al[u & 1];
    u16* LAn = Al[(u + 1) & 1];
    const bool st = (u + 1) < NT;
    bf16x8 bfr[4][2], af[2][2];

    // ---- phase 1: all B frags + A m0,m1; issue A(u+1) (reg-loads or gl_lds) ----
#pragma unroll
    for (int n = 0; n < 4; ++n) {
      bfr[n][0] = ldf(Bl + bB + n * 1024 + sw0);
      bfr[n][1] = ldf(Bl + bB + n * 1024 + sw1);
    }
    af[0][0] = ldf(LA + aB + sw0);        af[0][1] = ldf(LA + aB + sw1);
    af[1][0] = ldf(LA + aB + 1024 + sw0); af[1][1] = ldf(LA + aB + 1024 + sw1);
    if (st) { if (A_F32) aloadR(u + 1); else stageA16(u + 1, LAn); }
    __builtin_amdgcn_s_barrier();
    asm volatile("s_waitcnt lgkmcnt(0)" ::: "memory");
    __builtin_amdgcn_sched_barrier(0);
    __builtin_amdgcn_s_setprio(1);
#pragma unroll
    for (int m = 0; m < 2; ++m)
#pragma unroll
      for (int n = 0; n < 4; ++n) {
        acc[m][n] = __builtin_amdgcn_mfma_f32_16x16x32_bf16(af[m][0], bfr[n][0], acc[m][n], 0, 0, 0);
        acc[m][n] = __builtin_amdgcn_mfma_f32_16x16x32_bf16(af[m][1], bfr[n][1], acc[m][n], 0, 0, 0);
      }
    __builtin_amdgcn_s_setprio(0);
    __builtin_amdgcn_s_barrier();  // closes all waves' B reads of tile u

    // ---- phase 2: A m2,m3; stage B(u+1); (fused) convert+write A(u+1) ----
    af[0][0] = ldf(LA + aB + 2048 + sw0); af[0][1] = ldf(LA + aB + 2048 + sw1);
    af[1][0] = ldf(LA + aB + 3072 + sw0); af[1][1] = ldf(LA + aB + 3072 + sw1);
    if (st) stageB(u + 1);
    __builtin_amdgcn_s_barrier();
    asm volatile("s_waitcnt lgkmcnt(0)" ::: "memory");
    __builtin_amdgcn_sched_barrier(0);
    __builtin_amdgcn_s_setprio(1);
#pragma unroll
    for (int m = 0; m < 2; ++m)
#pragma unroll
      for (int n = 0; n < 4; ++n) {
        acc[2 + m][n] = __builtin_amdgcn_mfma_f32_16x16x32_bf16(af[m][0], bfr[n][0], acc[2 + m][n], 0, 0, 0);
        acc[2 + m][n] = __builtin_amdgcn_mfma_f32_16x16x32_bf16(af[m][1], bfr[n][1], acc[2 + m][n], 0, 0, 0);
      }
    __builtin_amdgcn_s_setprio(0);
    if (A_F32 && st) {
      asm volatile("s_waitcnt vmcnt(4)" ::: "memory");  // A reg-loads landed (B's 4 younger)
      awrite(LAn);
      asm volatile("s_waitcnt lgkmcnt(0)" ::: "memory");  // own ds_writes drained
    }
    asm volatile("s_waitcnt vmcnt(0)" ::: "memory");  // staged B(u+1) (and A gl_lds) landed
    __builtin_amdgcn_s_barrier();
  }

  // epilogue: C write
#pragma unroll
  for (int m = 0; m < 4; ++m)
#pragma unroll
    for (int n = 0; n < 4; ++n)
#pragma unroll
      for (int j = 0; j < 4; ++j) {
        size_t r = row0 + wm * 64 + m * 16 + g4 * 4 + j;
        size_t c = col0 + wn * 64 + n * 16 + ro;
        if (OUT_F32)
          reinterpret_cast<float*>(Cp)[r * N + c] = acc[m][n][j];
        else
          reinterpret_cast<u16*>(Cp)[r * N + c] = f2bf(acc[m][n][j]);
      }
}

// ---------------- window attention ----------------
// grid: b*512 + w*8 + h  (2048 blocks), 512 threads (8 waves, 32 q-rows each).
// K in LDS via global_load_lds with pre-swizzled source (32KB); V transposed in
// LDS, XOR-swizzled (32KB); P per-wave quarter-split, XOR-swizzled (16KB).
// Total exactly 80KB -> 2 blocks/CU.
__global__ __launch_bounds__(512, 4) void attn_kernel(const u16* __restrict__ qp,
                                                      const u16* __restrict__ kvp,
                                                      u16* __restrict__ o) {
  __shared__ __align__(16) u16 Kl[256 * 64];
  __shared__ __align__(16) u16 Vt[64 * 256];
  __shared__ __align__(16) u16 Pl[8 * 1024];
  const int bid = blockIdx.x;
  const int h = bid & 7, w = (bid >> 3) & 63, b = bid >> 9;
  const int w1 = w >> 3, w2 = w & 7;
  const int tid = threadIdx.x, lane = tid & 63, wv = tid >> 6;

  auto lrow = [&](int t) { return (w1 * 16 + (t >> 4)) * 128 + w2 * 16 + (t & 15); };

  // stage K: 2048 16B chunks; LDS dest linear; global source pre-swizzled g^(r&7).
#pragma unroll
  for (int p = 0; p < 4; ++p) {
    int ci = tid + p * 512;
    int r = ci >> 3, g = (ci & 7) ^ (r & 7);
    gl_lds16(kvp + ((size_t)(b * LL + lrow(r))) * 1024 + h * 64 + g * 8, Kl + ci * 8);
  }
  // stage V transposed, swizzled: (d, tk) at phys d*256 + ((tk>>3)^(d&7))*8 + (tk&7)
  {
    const int tk = tid >> 1, half = tid & 1;
    const size_t base = ((size_t)(b * LL + lrow(tk))) * 1024 + 512 + h * 64 + half * 32;
#pragma unroll
    for (int c = 0; c < 4; ++c) {
      u16x8 vx = *reinterpret_cast<const u16x8*>(kvp + base + c * 8);
#pragma unroll
      for (int e = 0; e < 8; ++e) {
        int d = half * 32 + c * 8 + e;
        Vt[d * 256 + (((tk >> 3) ^ (d & 7)) * 8) + (tk & 7)] = vx[e];
      }
    }
  }
  __syncthreads();

  const int ro = lane & 15;       // low nibble
  const int g4 = lane >> 4;       // lane group 0..3
  const float scale = 0.125f;     // hd^-0.5, hd=64
  const int swA = (g4 ^ (ro & 7)) * 8;
  const int swB = ((g4 + 4) ^ (ro & 7)) * 8;
  u16* PW = Pl + wv * 1024;

  auto ldf = [&](const u16* p) { return *reinterpret_cast<const bf16x8*>(p); };

#pragma unroll
  for (int rt = 0; rt < 2; ++rt) {
    // Q fragments for this 16-row tile, direct from global
    const int tq = 32 * wv + 16 * rt + ro;
    const size_t qbase = ((size_t)(b * LL + lrow(tq))) * 512 + h * 64 + g4 * 8;
    const bf16x8 qf0 = *reinterpret_cast<const bf16x8*>(qp + qbase);
    const bf16x8 qf1 = *reinterpret_cast<const bf16x8*>(qp + qbase + 32);

    // S = Q K^T : 16 q-rows x 256 keys; K frags from swizzled LDS
    f32x4 sa[16] = {};
    __builtin_amdgcn_s_setprio(1);
#pragma unroll
    for (int ct = 0; ct < 16; ++ct) {
      bf16x8 kf0 = ldf(Kl + (16 * ct + ro) * 64 + swA);
      bf16x8 kf1 = ldf(Kl + (16 * ct + ro) * 64 + swB);
      sa[ct] = __builtin_amdgcn_mfma_f32_16x16x32_bf16(qf0, kf0, sa[ct], 0, 0, 0);
      sa[ct] = __builtin_amdgcn_mfma_f32_16x16x32_bf16(qf1, kf1, sa[ct], 0, 0, 0);
    }
    __builtin_amdgcn_s_setprio(0);

    // softmax per q-row (row = g4*4 + j, key = 16*ct + ro)
#pragma unroll
    for (int j = 0; j < 4; ++j) {
      float m = -1e30f;
#pragma unroll
      for (int ct = 0; ct < 16; ++ct) m = fmaxf(m, sa[ct][j]);
      m = fmaxf(m, __shfl_xor(m, 1));
      m = fmaxf(m, __shfl_xor(m, 2));
      m = fmaxf(m, __shfl_xor(m, 4));
      m = fmaxf(m, __shfl_xor(m, 8));
      m *= scale;
      float s = 0.f;
#pragma unroll
      for (int ct = 0; ct < 16; ++ct) {
        float p = __expf(sa[ct][j] * scale - m);
        sa[ct][j] = p;
        s += p;
      }
      s += __shfl_xor(s, 1);
      s += __shfl_xor(s, 2);
      s += __shfl_xor(s, 4);
      s += __shfl_xor(s, 8);
      float inv = 1.f / s;
#pragma unroll
      for (int ct = 0; ct < 16; ++ct) sa[ct][j] *= inv;
    }

    // O = P V in four key-quarters through the per-wave swizzled LDS P tile.
    f32x4 oacc[4] = {};
#pragma unroll
    for (int kh = 0; kh < 4; ++kh) {
#pragma unroll
      for (int c = 0; c < 4; ++c)
#pragma unroll
        for (int j = 0; j < 4; ++j) {
          int rq = g4 * 4 + j;
          PW[rq * 64 + (((2 * c + (ro >> 3)) ^ (rq & 7)) * 8) + (ro & 7)] =
              f2bf(sa[kh * 4 + c][j]);
        }
      __builtin_amdgcn_s_setprio(1);
#pragma unroll
      for (int ks = 0; ks < 2; ++ks) {
        bf16x8 pf = ldf(PW + ro * 64 + (((ks * 4 + g4) ^ (ro & 7)) * 8));
        const int kkg = kh * 2 + ks;
#pragma unroll
        for (int cd = 0; cd < 4; ++cd) {
          bf16x8 vf = ldf(Vt + (16 * cd + ro) * 256 + (((kkg * 4 + g4) ^ (ro & 7)) * 8));
          oacc[cd] = __builtin_amdgcn_mfma_f32_16x16x32_bf16(pf, vf, oacc[cd], 0, 0, 0);
        }
      }
      __builtin_amdgcn_s_setprio(0);
    }

    // write out this 16-row tile
#pragma unroll
    for (int cd = 0; cd < 4; ++cd)
#pragma unroll
      for (int j = 0; j < 4; ++j) {
        int t = 32 * wv + 16 * rt + g4 * 4 + j;
        int d = 16 * cd + ro;
        o[((size_t)(b * LL + lrow(t))) * 512 + h * 64 + d] = f2bf(oacc[cd][j]);
      }
  }
}

// ---------------- launch ----------------
extern "C" void kernel_launch(void* const* d_in, const int* in_sizes, int n_in,
                              void* d_out, int out_size, void* d_ws, size_t ws_size,
                              hipStream_t stream) {
  const float* q = (const float*)d_in[0];
  const float* kv = (const float*)d_in[1];
  const float* Wq = (const float*)d_in[2];
  const float* Wkv = (const float*)d_in[3];
  const float* Wfc = (const float*)d_in[4];
  float* out = (float*)d_out;
  char* ws = (char*)d_ws;

  // workspace layout (bytes)
  u16* o_buf = (u16*)(ws + 0);            // 67108864
  u16* qp    = (u16*)(ws + 134217728);    // 67108864
  u16* kvp   = (u16*)(ws + 201326592);    // 134217728
  u16* Wq_t  = (u16*)(ws + 335544320);    // 524288
  u16* Wkv_t = (u16*)(ws + 336068608);    // 1048576
  u16* Wfc_t = (u16*)(ws + 337117184);    // 524288

  tcvt_kernel<<<256, 256, 0, stream>>>(Wq, Wkv, Wfc, Wq_t, Wkv_t, Wfc_t);

  gemm128<true, false><<<2048, 256, 0, stream>>>(q, Wq_t, qp, CC, 2);
  gemm128<true, false><<<4096, 256, 0, stream>>>(kv, Wkv_t, kvp, 2 * CC, 3);

  attn_kernel<<<BB * 64 * 8, 512, 0, stream>>>(qp, kvp, o_buf);

  gemm128<false, true><<<2048, 256, 0, stream>>>(o_buf, Wfc_t, out, CC, 2);
}

// Round 14
// 341.937 us; speedup vs baseline: 1.1770x; 1.1770x over previous
//
#include <hip/hip_runtime.h>
#include <stdint.h>

#define BB 4
#define LL 16384
#define CC 512
#define MM (BB * LL)  // 65536

typedef unsigned short u16;
typedef __bf16 bf16x8 __attribute__((ext_vector_type(8)));
typedef float f32x4 __attribute__((ext_vector_type(4)));
typedef u16 u16x8 __attribute__((ext_vector_type(8)));
typedef u16 u16x4 __attribute__((ext_vector_type(4)));

__device__ __forceinline__ u16 f2bf(float f) {
  return __builtin_bit_cast(u16, (__bf16)f);
}

__device__ __forceinline__ void gl_lds16(const void* g, void* l) {
  __builtin_amdgcn_global_load_lds((const __attribute__((address_space(1))) void*)g,
                                   (__attribute__((address_space(3))) void*)l,
                                   16, 0, 0);
}

// ---------------- fused prep: fp32->bf16 cvt (q,kv) + weight transpose-cvt ----------
// cvt layout: block b owns a 256KB fp32 span; thread t's k-th load is at
// base + k*4KB + t*16B -> every instruction is lane-dense (16 cache lines, not
// 64) AND 16 loads are in flight per thread.
__global__ __launch_bounds__(256) void prep_kernel(
    const float* __restrict__ q, const float* __restrict__ kv,
    const float* __restrict__ Wq, const float* __restrict__ Wkv,
    const float* __restrict__ Wfc, u16* __restrict__ qo, u16* __restrict__ kvo,
    u16* __restrict__ Wq_t, u16* __restrict__ Wkv_t, u16* __restrict__ Wfc_t) {
  __shared__ float tile[64][65];
  const int bid = blockIdx.x, tid = threadIdx.x;

  if (bid < 4096) {
    const int half = bid >> 11;
    const float* src = half ? kv : q;
    u16* dst = half ? kvo : qo;
    const int lb = bid & 2047;
    // block owns 16384 f32x4 chunks (256KB fp32); 4096 per k-step? No:
    // n4 = 8388608 chunks/array, 2048 blocks -> 4096 chunks/block, 16/thread.
    const int c0 = lb * 4096;
    f32x4 v[16];
#pragma unroll
    for (int k = 0; k < 16; ++k)
      v[k] = __builtin_nontemporal_load(reinterpret_cast<const f32x4*>(src) + c0 + k * 256 + tid);
#pragma unroll
    for (int k = 0; k < 8; ++k) {
      u16x8 o;
#pragma unroll
      for (int e = 0; e < 4; ++e) o[e] = f2bf(v[2 * k][e]);
#pragma unroll
      for (int e = 0; e < 4; ++e) o[4 + e] = f2bf(v[2 * k + 1][e]);
      // chunks 2k,2k+1 are at c0 + 2k*256 + ... not adjacent; store each half
      // separately as u16x4 to its own chunk position (dense per instruction).
      *reinterpret_cast<u16x4*>(dst + (size_t)(c0 + 2 * k * 256 + tid) * 4) =
          (u16x4){o[0], o[1], o[2], o[3]};
      *reinterpret_cast<u16x4*>(dst + (size_t)(c0 + (2 * k + 1) * 256 + tid) * 4) =
          (u16x4){o[4], o[5], o[6], o[7]};
    }
    return;
  }

  // weight transpose: W[K][N] -> Wt[N][K] bf16, 64x64 tiles
  const int wb = bid - 4096;
  const float* W; u16* Wt; int N, ti;
  if (wb < 64)       { W = Wq;  Wt = Wq_t;  N = 512;  ti = wb; }
  else if (wb < 192) { W = Wkv; Wt = Wkv_t; N = 1024; ti = wb - 64; }
  else               { W = Wfc; Wt = Wfc_t; N = 512;  ti = wb - 192; }
  const int ntn = N >> 6;
  const int kt = ti / ntn, nt = ti % ntn;
  const int k0 = kt << 6, n0 = nt << 6;
  {
    const int r = tid >> 4, c4 = tid & 15;
#pragma unroll
    for (int e = 0; e < 4; ++e) {
      int row = r + e * 16;
      f32x4 v = *reinterpret_cast<const f32x4*>(&W[(size_t)(k0 + row) * N + n0 + c4 * 4]);
      tile[row][c4 * 4 + 0] = v[0]; tile[row][c4 * 4 + 1] = v[1];
      tile[row][c4 * 4 + 2] = v[2]; tile[row][c4 * 4 + 3] = v[3];
    }
  }
  __syncthreads();
  {
    const int n = tid >> 2, qd = tid & 3;
#pragma unroll
    for (int e = 0; e < 2; ++e) {
      int c = qd * 2 + e;
      u16x8 o;
#pragma unroll
      for (int j = 0; j < 8; ++j) o[j] = f2bf(tile[c * 8 + j][n]);
      *reinterpret_cast<u16x8*>(&Wt[(size_t)(n0 + n) * 512 + k0 + c * 8]) = o;
    }
  }
}

// ---------------- 256x256 8-phase NT GEMM (round-10 config, known-good) ----------
// BM=BN=256, BK=64, 8 waves. TRIPLE-buffered A + double-buffered B (160KB LDS):
// both operands staged 2 K-tiles ahead; end-of-tile vmcnt(8) drains loads issued
// a full tile earlier. Race ledger as derived in round 9/10.
template <bool OUT_F32>
__global__ __launch_bounds__(512, 2) void gemm256(const u16* __restrict__ A,
                                                  const u16* __restrict__ Bt,
                                                  void* __restrict__ Cp,
                                                  int M, int N, int K) {
  __shared__ __align__(16) u16 Al[3][16384];
  __shared__ __align__(16) u16 Bl[2][16384];
  const int nbn = N >> 8;
  const int nwg = gridDim.x;
  const int bid0 = blockIdx.x;
  const int cpx = nwg >> 3;
  const int bid = (bid0 & 7) * cpx + (bid0 >> 3);
  const int bm = bid / nbn, bn = bid % nbn;
  const size_t row0 = (size_t)bm << 8, col0 = (size_t)bn << 8;
  const int tid = threadIdx.x, lane = tid & 63;
  const int wv = tid >> 6, wm = wv >> 2, wn = wv & 3;
  const int ro = lane & 15, g4 = lane >> 4;
  const int NT = K >> 6;

  const int ci0 = tid, ci1 = tid + 512;
  const int r0 = ci0 >> 3, g0 = (ci0 & 7) ^ (r0 & 7);
  const int r1 = ci1 >> 3, g1 = (ci1 & 7) ^ (r1 & 7);

  auto stageA = [&](int half, int kt, u16* L) {
    gl_lds16(A + (row0 + half * 128 + r0) * (size_t)K + kt * 64 + g0 * 8, L + half * 8192 + ci0 * 8);
    gl_lds16(A + (row0 + half * 128 + r1) * (size_t)K + kt * 64 + g1 * 8, L + half * 8192 + ci1 * 8);
  };
  auto stageB = [&](int half, int kt, u16* L) {
    gl_lds16(Bt + (col0 + half * 128 + r0) * (size_t)K + kt * 64 + g0 * 8, L + half * 8192 + ci0 * 8);
    gl_lds16(Bt + (col0 + half * 128 + r1) * (size_t)K + kt * 64 + g1 * 8, L + half * 8192 + ci1 * 8);
  };

  const int aB = (wm * 128 + ro) * 64;
  const int bB = (wn * 64 + ro) * 64;
  const int sw0 = (g4 ^ (ro & 7)) * 8;
  const int sw1 = ((g4 + 4) ^ (ro & 7)) * 8;

  auto ldf = [&](const u16* p) { return *reinterpret_cast<const bf16x8*>(p); };

  f32x4 acc[8][4] = {};

  stageA(0, 0, Al[0]); stageA(1, 0, Al[0]);
  stageB(0, 0, Bl[0]); stageB(1, 0, Bl[0]);
  stageA(0, 1, Al[1]); stageA(1, 1, Al[1]);
  stageB(0, 1, Bl[1]); stageB(1, 1, Bl[1]);
  asm volatile("s_waitcnt vmcnt(8)" ::: "memory");
  __builtin_amdgcn_s_barrier();

  u16 *Acur = Al[0], *Anxt = Al[1], *Asta = Al[2];
  u16 *Bcur = Bl[0], *Bnxt = Bl[1];

  for (int u = 0; u < NT; ++u) {
    const bool st = (u + 2) < NT;
    bf16x8 bfr[4][2], af[2][2];

#pragma unroll
    for (int n = 0; n < 4; ++n) {
      bfr[n][0] = ldf(Bcur + bB + n * 1024 + sw0);
      bfr[n][1] = ldf(Bcur + bB + n * 1024 + sw1);
    }
    af[0][0] = ldf(Acur + aB + sw0);        af[0][1] = ldf(Acur + aB + sw1);
    af[1][0] = ldf(Acur + aB + 1024 + sw0); af[1][1] = ldf(Acur + aB + 1024 + sw1);
    if (st) stageA(0, u + 2, Asta);
    __builtin_amdgcn_s_barrier();
    asm volatile("s_waitcnt lgkmcnt(0)" ::: "memory");
    __builtin_amdgcn_sched_barrier(0);
    __builtin_amdgcn_s_setprio(1);
#pragma unroll
    for (int m = 0; m < 2; ++m)
#pragma unroll
      for (int n = 0; n < 4; ++n) {
        acc[m][n] = __builtin_amdgcn_mfma_f32_16x16x32_bf16(af[m][0], bfr[n][0], acc[m][n], 0, 0, 0);
        acc[m][n] = __builtin_amdgcn_mfma_f32_16x16x32_bf16(af[m][1], bfr[n][1], acc[m][n], 0, 0, 0);
      }
    __builtin_amdgcn_s_setprio(0);
    __builtin_amdgcn_s_barrier();

#pragma unroll
    for (int ph = 1; ph < 4; ++ph) {
      af[0][0] = ldf(Acur + aB + (2 * ph) * 1024 + sw0);
      af[0][1] = ldf(Acur + aB + (2 * ph) * 1024 + sw1);
      af[1][0] = ldf(Acur + aB + (2 * ph + 1) * 1024 + sw0);
      af[1][1] = ldf(Acur + aB + (2 * ph + 1) * 1024 + sw1);
      if (ph == 1) { if (st) { stageA(1, u + 2, Asta); stageB(0, u + 2, Bcur); } }
      else if (ph == 2) { if (st) stageB(1, u + 2, Bcur); }
      __builtin_amdgcn_s_barrier();
      asm volatile("s_waitcnt lgkmcnt(0)" ::: "memory");
      __builtin_amdgcn_sched_barrier(0);
      __builtin_amdgcn_s_setprio(1);
#pragma unroll
      for (int m = 0; m < 2; ++m)
#pragma unroll
        for (int n = 0; n < 4; ++n) {
          acc[2 * ph + m][n] =
              __builtin_amdgcn_mfma_f32_16x16x32_bf16(af[m][0], bfr[n][0], acc[2 * ph + m][n], 0, 0, 0);
          acc[2 * ph + m][n] =
              __builtin_amdgcn_mfma_f32_16x16x32_bf16(af[m][1], bfr[n][1], acc[2 * ph + m][n], 0, 0, 0);
        }
      __builtin_amdgcn_s_setprio(0);
      if (ph == 3) {
        if (st) asm volatile("s_waitcnt vmcnt(8)" ::: "memory");
        else    asm volatile("s_waitcnt vmcnt(0)" ::: "memory");
      }
      __builtin_amdgcn_s_barrier();
    }

    u16* ta = Acur; Acur = Anxt; Anxt = Asta; Asta = ta;
    u16* tb = Bcur; Bcur = Bnxt; Bnxt = tb;
  }

#pragma unroll
  for (int m = 0; m < 8; ++m)
#pragma unroll
    for (int n = 0; n < 4; ++n)
#pragma unroll
      for (int j = 0; j < 4; ++j) {
        size_t r = row0 + wm * 128 + m * 16 + g4 * 4 + j;
        size_t c = col0 + wn * 64 + n * 16 + ro;
        if (OUT_F32)
          reinterpret_cast<float*>(Cp)[r * N + c] = acc[m][n][j];
        else
          reinterpret_cast<u16*>(Cp)[r * N + c] = f2bf(acc[m][n][j]);
      }
}

// ---------------- window attention (round-6 structure, known-good) ----------------
__global__ __launch_bounds__(512, 4) void attn_kernel(const u16* __restrict__ qp,
                                                      const u16* __restrict__ kvp,
                                                      u16* __restrict__ o) {
  __shared__ __align__(16) u16 Kl[256 * 64];
  __shared__ __align__(16) u16 Vt[64 * 256];
  __shared__ __align__(16) u16 Pl[8 * 1024];
  const int bid = blockIdx.x;
  const int h = bid & 7, w = (bid >> 3) & 63, b = bid >> 9;
  const int w1 = w >> 3, w2 = w & 7;
  const int tid = threadIdx.x, lane = tid & 63, wv = tid >> 6;

  auto lrow = [&](int t) { return (w1 * 16 + (t >> 4)) * 128 + w2 * 16 + (t & 15); };

#pragma unroll
  for (int p = 0; p < 4; ++p) {
    int ci = tid + p * 512;
    int r = ci >> 3, g = (ci & 7) ^ (r & 7);
    gl_lds16(kvp + ((size_t)(b * LL + lrow(r))) * 1024 + h * 64 + g * 8, Kl + ci * 8);
  }
  {
    const int tk = tid >> 1, half = tid & 1;
    const size_t base = ((size_t)(b * LL + lrow(tk))) * 1024 + 512 + h * 64 + half * 32;
#pragma unroll
    for (int c = 0; c < 4; ++c) {
      u16x8 vx = *reinterpret_cast<const u16x8*>(kvp + base + c * 8);
#pragma unroll
      for (int e = 0; e < 8; ++e) {
        int d = half * 32 + c * 8 + e;
        Vt[d * 256 + (((tk >> 3) ^ (d & 7)) * 8) + (tk & 7)] = vx[e];
      }
    }
  }
  __syncthreads();

  const int ro = lane & 15;
  const int g4 = lane >> 4;
  const float scale = 0.125f;
  const int swA = (g4 ^ (ro & 7)) * 8;
  const int swB = ((g4 + 4) ^ (ro & 7)) * 8;
  u16* PW = Pl + wv * 1024;

  auto ldf = [&](const u16* p) { return *reinterpret_cast<const bf16x8*>(p); };

#pragma unroll
  for (int rt = 0; rt < 2; ++rt) {
    const int tq = 32 * wv + 16 * rt + ro;
    const size_t qbase = ((size_t)(b * LL + lrow(tq))) * 512 + h * 64 + g4 * 8;
    const bf16x8 qf0 = *reinterpret_cast<const bf16x8*>(qp + qbase);
    const bf16x8 qf1 = *reinterpret_cast<const bf16x8*>(qp + qbase + 32);

    f32x4 sa[16] = {};
    __builtin_amdgcn_s_setprio(1);
#pragma unroll
    for (int ct = 0; ct < 16; ++ct) {
      bf16x8 kf0 = ldf(Kl + (16 * ct + ro) * 64 + swA);
      bf16x8 kf1 = ldf(Kl + (16 * ct + ro) * 64 + swB);
      sa[ct] = __builtin_amdgcn_mfma_f32_16x16x32_bf16(qf0, kf0, sa[ct], 0, 0, 0);
      sa[ct] = __builtin_amdgcn_mfma_f32_16x16x32_bf16(qf1, kf1, sa[ct], 0, 0, 0);
    }
    __builtin_amdgcn_s_setprio(0);

#pragma unroll
    for (int j = 0; j < 4; ++j) {
      float m = -1e30f;
#pragma unroll
      for (int ct = 0; ct < 16; ++ct) m = fmaxf(m, sa[ct][j]);
      m = fmaxf(m, __shfl_xor(m, 1));
      m = fmaxf(m, __shfl_xor(m, 2));
      m = fmaxf(m, __shfl_xor(m, 4));
      m = fmaxf(m, __shfl_xor(m, 8));
      m *= scale;
      float s = 0.f;
#pragma unroll
      for (int ct = 0; ct < 16; ++ct) {
        float p = __expf(sa[ct][j] * scale - m);
        sa[ct][j] = p;
        s += p;
      }
      s += __shfl_xor(s, 1);
      s += __shfl_xor(s, 2);
      s += __shfl_xor(s, 4);
      s += __shfl_xor(s, 8);
      float inv = 1.f / s;
#pragma unroll
      for (int ct = 0; ct < 16; ++ct) sa[ct][j] *= inv;
    }

    f32x4 oacc[4] = {};
#pragma unroll
    for (int kh = 0; kh < 4; ++kh) {
#pragma unroll
      for (int c = 0; c < 4; ++c)
#pragma unroll
        for (int j = 0; j < 4; ++j) {
          int rq = g4 * 4 + j;
          PW[rq * 64 + (((2 * c + (ro >> 3)) ^ (rq & 7)) * 8) + (ro & 7)] =
              f2bf(sa[kh * 4 + c][j]);
        }
      __builtin_amdgcn_s_setprio(1);
#pragma unroll
      for (int ks = 0; ks < 2; ++ks) {
        bf16x8 pf = ldf(PW + ro * 64 + (((ks * 4 + g4) ^ (ro & 7)) * 8));
        const int kkg = kh * 2 + ks;
#pragma unroll
        for (int cd = 0; cd < 4; ++cd) {
          bf16x8 vf = ldf(Vt + (16 * cd + ro) * 256 + (((kkg * 4 + g4) ^ (ro & 7)) * 8));
          oacc[cd] = __builtin_amdgcn_mfma_f32_16x16x32_bf16(pf, vf, oacc[cd], 0, 0, 0);
        }
      }
      __builtin_amdgcn_s_setprio(0);
    }

#pragma unroll
    for (int cd = 0; cd < 4; ++cd)
#pragma unroll
      for (int j = 0; j < 4; ++j) {
        int t = 32 * wv + 16 * rt + g4 * 4 + j;
        int d = 16 * cd + ro;
        o[((size_t)(b * LL + lrow(t))) * 512 + h * 64 + d] = f2bf(oacc[cd][j]);
      }
  }
}

// ---------------- launch ----------------
extern "C" void kernel_launch(void* const* d_in, const int* in_sizes, int n_in,
                              void* d_out, int out_size, void* d_ws, size_t ws_size,
                              hipStream_t stream) {
  const float* q = (const float*)d_in[0];
  const float* kv = (const float*)d_in[1];
  const float* Wq = (const float*)d_in[2];
  const float* Wkv = (const float*)d_in[3];
  const float* Wfc = (const float*)d_in[4];
  float* out = (float*)d_out;
  char* ws = (char*)d_ws;

  u16* q_bf  = (u16*)(ws + 0);            // 67108864  (also reused as o_buf)
  u16* kv_bf = (u16*)(ws + 67108864);     // 67108864
  u16* qp    = (u16*)(ws + 134217728);    // 67108864
  u16* kvp   = (u16*)(ws + 201326592);    // 134217728
  u16* Wq_t  = (u16*)(ws + 335544320);    // 524288
  u16* Wkv_t = (u16*)(ws + 336068608);    // 1048576
  u16* Wfc_t = (u16*)(ws + 337117184);    // 524288
  u16* o_buf = q_bf;

  prep_kernel<<<4352, 256, 0, stream>>>(q, kv, Wq, Wkv, Wfc, q_bf, kv_bf, Wq_t, Wkv_t, Wfc_t);

  gemm256<false><<<(MM / 256) * (CC / 256), 512, 0, stream>>>(q_bf, Wq_t, qp, MM, CC, CC);
  gemm256<false><<<(MM / 256) * (2 * CC / 256), 512, 0, stream>>>(kv_bf, Wkv_t, kvp, MM, 2 * CC, CC);

  attn_kernel<<<BB * 64 * 8, 512, 0, stream>>>(qp, kvp, o_buf);

  gemm256<true><<<(MM / 256) * (CC / 256), 512, 0, stream>>>(o_buf, Wfc_t, out, MM, CC, CC);
}

// Round 15
// 341.406 us; speedup vs baseline: 1.1789x; 1.0016x over previous
//
#include <hip/hip_runtime.h>
#include <stdint.h>

#define BB 4
#define LL 16384
#define CC 512
#define MM (BB * LL)  // 65536

typedef unsigned short u16;
typedef __bf16 bf16x8 __attribute__((ext_vector_type(8)));
typedef float f32x4 __attribute__((ext_vector_type(4)));
typedef u16 u16x8 __attribute__((ext_vector_type(8)));
typedef u16 u16x4 __attribute__((ext_vector_type(4)));

__device__ __forceinline__ u16 f2bf(float f) {
  return __builtin_bit_cast(u16, (__bf16)f);
}

__device__ __forceinline__ void gl_lds16(const void* g, void* l) {
  __builtin_amdgcn_global_load_lds((const __attribute__((address_space(1))) void*)g,
                                   (__attribute__((address_space(3))) void*)l,
                                   16, 0, 0);
}

// ---------------- fused prep: fp32->bf16 cvt (q,kv) + weight transpose-cvt ----------
// cvt layout: dense per-instruction coalescing AND 16 loads in flight (round 14,
// confirmed win).
__global__ __launch_bounds__(256) void prep_kernel(
    const float* __restrict__ q, const float* __restrict__ kv,
    const float* __restrict__ Wq, const float* __restrict__ Wkv,
    const float* __restrict__ Wfc, u16* __restrict__ qo, u16* __restrict__ kvo,
    u16* __restrict__ Wq_t, u16* __restrict__ Wkv_t, u16* __restrict__ Wfc_t) {
  __shared__ float tile[64][65];
  const int bid = blockIdx.x, tid = threadIdx.x;

  if (bid < 4096) {
    const int half = bid >> 11;
    const float* src = half ? kv : q;
    u16* dst = half ? kvo : qo;
    const int lb = bid & 2047;
    const int c0 = lb * 4096;
    f32x4 v[16];
#pragma unroll
    for (int k = 0; k < 16; ++k)
      v[k] = __builtin_nontemporal_load(reinterpret_cast<const f32x4*>(src) + c0 + k * 256 + tid);
#pragma unroll
    for (int k = 0; k < 8; ++k) {
      u16x8 o;
#pragma unroll
      for (int e = 0; e < 4; ++e) o[e] = f2bf(v[2 * k][e]);
#pragma unroll
      for (int e = 0; e < 4; ++e) o[4 + e] = f2bf(v[2 * k + 1][e]);
      *reinterpret_cast<u16x4*>(dst + (size_t)(c0 + 2 * k * 256 + tid) * 4) =
          (u16x4){o[0], o[1], o[2], o[3]};
      *reinterpret_cast<u16x4*>(dst + (size_t)(c0 + (2 * k + 1) * 256 + tid) * 4) =
          (u16x4){o[4], o[5], o[6], o[7]};
    }
    return;
  }

  // weight transpose: W[K][N] -> Wt[N][K] bf16, 64x64 tiles
  const int wb = bid - 4096;
  const float* W; u16* Wt; int N, ti;
  if (wb < 64)       { W = Wq;  Wt = Wq_t;  N = 512;  ti = wb; }
  else if (wb < 192) { W = Wkv; Wt = Wkv_t; N = 1024; ti = wb - 64; }
  else               { W = Wfc; Wt = Wfc_t; N = 512;  ti = wb - 192; }
  const int ntn = N >> 6;
  const int kt = ti / ntn, nt = ti % ntn;
  const int k0 = kt << 6, n0 = nt << 6;
  {
    const int r = tid >> 4, c4 = tid & 15;
#pragma unroll
    for (int e = 0; e < 4; ++e) {
      int row = r + e * 16;
      f32x4 v = *reinterpret_cast<const f32x4*>(&W[(size_t)(k0 + row) * N + n0 + c4 * 4]);
      tile[row][c4 * 4 + 0] = v[0]; tile[row][c4 * 4 + 1] = v[1];
      tile[row][c4 * 4 + 2] = v[2]; tile[row][c4 * 4 + 3] = v[3];
    }
  }
  __syncthreads();
  {
    const int n = tid >> 2, qd = tid & 3;
#pragma unroll
    for (int e = 0; e < 2; ++e) {
      int c = qd * 2 + e;
      u16x8 o;
#pragma unroll
      for (int j = 0; j < 8; ++j) o[j] = f2bf(tile[c * 8 + j][n]);
      *reinterpret_cast<u16x8*>(&Wt[(size_t)(n0 + n) * 512 + k0 + c * 8]) = o;
    }
  }
}

// ---------------- 256x256 NT GEMM, register-pipelined fragments ----------
// BM=BN=256, BK=64, 8 waves. TRIPLE-buffered A + double-buffered B in LDS
// (160KB), staged 2 K-tiles ahead, end-of-tile vmcnt(8) (round-10 ledger).
// NEW: A-fragment ds_reads are double-buffered in REGISTERS (afA/afB) and
// issued one phase ahead with counted lgkmcnt(4) waits, so DS traffic hides
// under the MFMA pipe instead of strictly alternating with it. Barriers: 2 per
// K-tile -- one after p0's MFMA (closes all waves' B reads -> stageB into Bcur
// safe), one at tile end (publishes staged tile u+1).
template <bool OUT_F32>
__global__ __launch_bounds__(512, 2) void gemm256(const u16* __restrict__ A,
                                                  const u16* __restrict__ Bt,
                                                  void* __restrict__ Cp,
                                                  int M, int N, int K) {
  __shared__ __align__(16) u16 Al[3][16384];
  __shared__ __align__(16) u16 Bl[2][16384];
  const int nbn = N >> 8;
  const int nwg = gridDim.x;
  const int bid0 = blockIdx.x;
  const int cpx = nwg >> 3;
  const int bid = (bid0 & 7) * cpx + (bid0 >> 3);
  const int bm = bid / nbn, bn = bid % nbn;
  const size_t row0 = (size_t)bm << 8, col0 = (size_t)bn << 8;
  const int tid = threadIdx.x, lane = tid & 63;
  const int wv = tid >> 6, wm = wv >> 2, wn = wv & 3;
  const int ro = lane & 15, g4 = lane >> 4;
  const int NT = K >> 6;

  const int ci0 = tid, ci1 = tid + 512;
  const int r0 = ci0 >> 3, g0 = (ci0 & 7) ^ (r0 & 7);
  const int r1 = ci1 >> 3, g1 = (ci1 & 7) ^ (r1 & 7);

  auto stageA = [&](int half, int kt, u16* L) {
    gl_lds16(A + (row0 + half * 128 + r0) * (size_t)K + kt * 64 + g0 * 8, L + half * 8192 + ci0 * 8);
    gl_lds16(A + (row0 + half * 128 + r1) * (size_t)K + kt * 64 + g1 * 8, L + half * 8192 + ci1 * 8);
  };
  auto stageB = [&](int half, int kt, u16* L) {
    gl_lds16(Bt + (col0 + half * 128 + r0) * (size_t)K + kt * 64 + g0 * 8, L + half * 8192 + ci0 * 8);
    gl_lds16(Bt + (col0 + half * 128 + r1) * (size_t)K + kt * 64 + g1 * 8, L + half * 8192 + ci1 * 8);
  };

  const int aB = (wm * 128 + ro) * 64;
  const int bB = (wn * 64 + ro) * 64;
  const int sw0 = (g4 ^ (ro & 7)) * 8;
  const int sw1 = ((g4 + 4) ^ (ro & 7)) * 8;

  auto ldf = [&](const u16* p) { return *reinterpret_cast<const bf16x8*>(p); };

  f32x4 acc[8][4] = {};

  stageA(0, 0, Al[0]); stageA(1, 0, Al[0]);
  stageB(0, 0, Bl[0]); stageB(1, 0, Bl[0]);
  stageA(0, 1, Al[1]); stageA(1, 1, Al[1]);
  stageB(0, 1, Bl[1]); stageB(1, 1, Bl[1]);
  asm volatile("s_waitcnt vmcnt(8)" ::: "memory");
  __builtin_amdgcn_s_barrier();

  u16 *Acur = Al[0], *Anxt = Al[1], *Asta = Al[2];
  u16 *Bcur = Bl[0], *Bnxt = Bl[1];

  for (int u = 0; u < NT; ++u) {
    const bool st = (u + 2) < NT;
    bf16x8 bfr[4][2], afA[2][2], afB[2][2];

    // ---- p0: read all B frags + A(m0,m1); stage A(u+2)h0 into freed buffer ----
#pragma unroll
    for (int n = 0; n < 4; ++n) {
      bfr[n][0] = ldf(Bcur + bB + n * 1024 + sw0);
      bfr[n][1] = ldf(Bcur + bB + n * 1024 + sw1);
    }
    afA[0][0] = ldf(Acur + aB + sw0);        afA[0][1] = ldf(Acur + aB + sw1);
    afA[1][0] = ldf(Acur + aB + 1024 + sw0); afA[1][1] = ldf(Acur + aB + 1024 + sw1);
    if (st) stageA(0, u + 2, Asta);
    asm volatile("s_waitcnt lgkmcnt(0)" ::: "memory");
    __builtin_amdgcn_sched_barrier(0);
    // issue A(m2,m3) fragment reads; they complete under p0's MFMA
    afB[0][0] = ldf(Acur + aB + 2048 + sw0); afB[0][1] = ldf(Acur + aB + 2048 + sw1);
    afB[1][0] = ldf(Acur + aB + 3072 + sw0); afB[1][1] = ldf(Acur + aB + 3072 + sw1);
    __builtin_amdgcn_sched_barrier(0);
    __builtin_amdgcn_s_setprio(1);
#pragma unroll
    for (int m = 0; m < 2; ++m)
#pragma unroll
      for (int n = 0; n < 4; ++n) {
        acc[m][n] = __builtin_amdgcn_mfma_f32_16x16x32_bf16(afA[m][0], bfr[n][0], acc[m][n], 0, 0, 0);
        acc[m][n] = __builtin_amdgcn_mfma_f32_16x16x32_bf16(afA[m][1], bfr[n][1], acc[m][n], 0, 0, 0);
      }
    __builtin_amdgcn_s_setprio(0);
    __builtin_amdgcn_s_barrier();  // all waves' B(+A0) reads of tile u complete

    // ---- p1: stage Ah1(u+2)+Bh0(u+2); issue A(m4,m5) reads; MFMA m2,m3 ----
    if (st) { stageA(1, u + 2, Asta); stageB(0, u + 2, Bcur); }
    afA[0][0] = ldf(Acur + aB + 4096 + sw0); afA[0][1] = ldf(Acur + aB + 4096 + sw1);
    afA[1][0] = ldf(Acur + aB + 5120 + sw0); afA[1][1] = ldf(Acur + aB + 5120 + sw1);
    asm volatile("s_waitcnt lgkmcnt(4)" ::: "memory");  // afB (m2,m3) ready
    __builtin_amdgcn_sched_barrier(0);
    __builtin_amdgcn_s_setprio(1);
#pragma unroll
    for (int m = 0; m < 2; ++m)
#pragma unroll
      for (int n = 0; n < 4; ++n) {
        acc[2 + m][n] = __builtin_amdgcn_mfma_f32_16x16x32_bf16(afB[m][0], bfr[n][0], acc[2 + m][n], 0, 0, 0);
        acc[2 + m][n] = __builtin_amdgcn_mfma_f32_16x16x32_bf16(afB[m][1], bfr[n][1], acc[2 + m][n], 0, 0, 0);
      }
    __builtin_amdgcn_s_setprio(0);

    // ---- p2: stage Bh1(u+2); issue A(m6,m7) reads; MFMA m4,m5 ----
    if (st) stageB(1, u + 2, Bcur);
    afB[0][0] = ldf(Acur + aB + 6144 + sw0); afB[0][1] = ldf(Acur + aB + 6144 + sw1);
    afB[1][0] = ldf(Acur + aB + 7168 + sw0); afB[1][1] = ldf(Acur + aB + 7168 + sw1);
    asm volatile("s_waitcnt lgkmcnt(4)" ::: "memory");  // afA (m4,m5) ready
    __builtin_amdgcn_sched_barrier(0);
    __builtin_amdgcn_s_setprio(1);
#pragma unroll
    for (int m = 0; m < 2; ++m)
#pragma unroll
      for (int n = 0; n < 4; ++n) {
        acc[4 + m][n] = __builtin_amdgcn_mfma_f32_16x16x32_bf16(afA[m][0], bfr[n][0], acc[4 + m][n], 0, 0, 0);
        acc[4 + m][n] = __builtin_amdgcn_mfma_f32_16x16x32_bf16(afA[m][1], bfr[n][1], acc[4 + m][n], 0, 0, 0);
      }
    __builtin_amdgcn_s_setprio(0);

    // ---- p3: MFMA m6,m7; tile-end drain + publish ----
    asm volatile("s_waitcnt lgkmcnt(0)" ::: "memory");  // afB (m6,m7) ready
    __builtin_amdgcn_sched_barrier(0);
    __builtin_amdgcn_s_setprio(1);
#pragma unroll
    for (int m = 0; m < 2; ++m)
#pragma unroll
      for (int n = 0; n < 4; ++n) {
        acc[6 + m][n] = __builtin_amdgcn_mfma_f32_16x16x32_bf16(afB[m][0], bfr[n][0], acc[6 + m][n], 0, 0, 0);
        acc[6 + m][n] = __builtin_amdgcn_mfma_f32_16x16x32_bf16(afB[m][1], bfr[n][1], acc[6 + m][n], 0, 0, 0);
      }
    __builtin_amdgcn_s_setprio(0);
    if (st) asm volatile("s_waitcnt vmcnt(8)" ::: "memory");
    else    asm volatile("s_waitcnt vmcnt(0)" ::: "memory");
    __builtin_amdgcn_s_barrier();

    u16* ta = Acur; Acur = Anxt; Anxt = Asta; Asta = ta;
    u16* tb = Bcur; Bcur = Bnxt; Bnxt = tb;
  }

#pragma unroll
  for (int m = 0; m < 8; ++m)
#pragma unroll
    for (int n = 0; n < 4; ++n)
#pragma unroll
      for (int j = 0; j < 4; ++j) {
        size_t r = row0 + wm * 128 + m * 16 + g4 * 4 + j;
        size_t c = col0 + wn * 64 + n * 16 + ro;
        if (OUT_F32)
          reinterpret_cast<float*>(Cp)[r * N + c] = acc[m][n][j];
        else
          reinterpret_cast<u16*>(Cp)[r * N + c] = f2bf(acc[m][n][j]);
      }
}

// ---------------- window attention (round-6 structure, known-good) ----------------
__global__ __launch_bounds__(512, 4) void attn_kernel(const u16* __restrict__ qp,
                                                      const u16* __restrict__ kvp,
                                                      u16* __restrict__ o) {
  __shared__ __align__(16) u16 Kl[256 * 64];
  __shared__ __align__(16) u16 Vt[64 * 256];
  __shared__ __align__(16) u16 Pl[8 * 1024];
  const int bid = blockIdx.x;
  const int h = bid & 7, w = (bid >> 3) & 63, b = bid >> 9;
  const int w1 = w >> 3, w2 = w & 7;
  const int tid = threadIdx.x, lane = tid & 63, wv = tid >> 6;

  auto lrow = [&](int t) { return (w1 * 16 + (t >> 4)) * 128 + w2 * 16 + (t & 15); };

#pragma unroll
  for (int p = 0; p < 4; ++p) {
    int ci = tid + p * 512;
    int r = ci >> 3, g = (ci & 7) ^ (r & 7);
    gl_lds16(kvp + ((size_t)(b * LL + lrow(r))) * 1024 + h * 64 + g * 8, Kl + ci * 8);
  }
  {
    const int tk = tid >> 1, half = tid & 1;
    const size_t base = ((size_t)(b * LL + lrow(tk))) * 1024 + 512 + h * 64 + half * 32;
#pragma unroll
    for (int c = 0; c < 4; ++c) {
      u16x8 vx = *reinterpret_cast<const u16x8*>(kvp + base + c * 8);
#pragma unroll
      for (int e = 0; e < 8; ++e) {
        int d = half * 32 + c * 8 + e;
        Vt[d * 256 + (((tk >> 3) ^ (d & 7)) * 8) + (tk & 7)] = vx[e];
      }
    }
  }
  __syncthreads();

  const int ro = lane & 15;
  const int g4 = lane >> 4;
  const float scale = 0.125f;
  const int swA = (g4 ^ (ro & 7)) * 8;
  const int swB = ((g4 + 4) ^ (ro & 7)) * 8;
  u16* PW = Pl + wv * 1024;

  auto ldf = [&](const u16* p) { return *reinterpret_cast<const bf16x8*>(p); };

#pragma unroll
  for (int rt = 0; rt < 2; ++rt) {
    const int tq = 32 * wv + 16 * rt + ro;
    const size_t qbase = ((size_t)(b * LL + lrow(tq))) * 512 + h * 64 + g4 * 8;
    const bf16x8 qf0 = *reinterpret_cast<const bf16x8*>(qp + qbase);
    const bf16x8 qf1 = *reinterpret_cast<const bf16x8*>(qp + qbase + 32);

    f32x4 sa[16] = {};
    __builtin_amdgcn_s_setprio(1);
#pragma unroll
    for (int ct = 0; ct < 16; ++ct) {
      bf16x8 kf0 = ldf(Kl + (16 * ct + ro) * 64 + swA);
      bf16x8 kf1 = ldf(Kl + (16 * ct + ro) * 64 + swB);
      sa[ct] = __builtin_amdgcn_mfma_f32_16x16x32_bf16(qf0, kf0, sa[ct], 0, 0, 0);
      sa[ct] = __builtin_amdgcn_mfma_f32_16x16x32_bf16(qf1, kf1, sa[ct], 0, 0, 0);
    }
    __builtin_amdgcn_s_setprio(0);

#pragma unroll
    for (int j = 0; j < 4; ++j) {
      float m = -1e30f;
#pragma unroll
      for (int ct = 0; ct < 16; ++ct) m = fmaxf(m, sa[ct][j]);
      m = fmaxf(m, __shfl_xor(m, 1));
      m = fmaxf(m, __shfl_xor(m, 2));
      m = fmaxf(m, __shfl_xor(m, 4));
      m = fmaxf(m, __shfl_xor(m, 8));
      m *= scale;
      float s = 0.f;
#pragma unroll
      for (int ct = 0; ct < 16; ++ct) {
        float p = __expf(sa[ct][j] * scale - m);
        sa[ct][j] = p;
        s += p;
      }
      s += __shfl_xor(s, 1);
      s += __shfl_xor(s, 2);
      s += __shfl_xor(s, 4);
      s += __shfl_xor(s, 8);
      float inv = 1.f / s;
#pragma unroll
      for (int ct = 0; ct < 16; ++ct) sa[ct][j] *= inv;
    }

    f32x4 oacc[4] = {};
#pragma unroll
    for (int kh = 0; kh < 4; ++kh) {
#pragma unroll
      for (int c = 0; c < 4; ++c)
#pragma unroll
        for (int j = 0; j < 4; ++j) {
          int rq = g4 * 4 + j;
          PW[rq * 64 + (((2 * c + (ro >> 3)) ^ (rq & 7)) * 8) + (ro & 7)] =
              f2bf(sa[kh * 4 + c][j]);
        }
      __builtin_amdgcn_s_setprio(1);
#pragma unroll
      for (int ks = 0; ks < 2; ++ks) {
        bf16x8 pf = ldf(PW + ro * 64 + (((ks * 4 + g4) ^ (ro & 7)) * 8));
        const int kkg = kh * 2 + ks;
#pragma unroll
        for (int cd = 0; cd < 4; ++cd) {
          bf16x8 vf = ldf(Vt + (16 * cd + ro) * 256 + (((kkg * 4 + g4) ^ (ro & 7)) * 8));
          oacc[cd] = __builtin_amdgcn_mfma_f32_16x16x32_bf16(pf, vf, oacc[cd], 0, 0, 0);
        }
      }
      __builtin_amdgcn_s_setprio(0);
    }

#pragma unroll
    for (int cd = 0; cd < 4; ++cd)
#pragma unroll
      for (int j = 0; j < 4; ++j) {
        int t = 32 * wv + 16 * rt + g4 * 4 + j;
        int d = 16 * cd + ro;
        o[((size_t)(b * LL + lrow(t))) * 512 + h * 64 + d] = f2bf(oacc[cd][j]);
      }
  }
}

// ---------------- launch ----------------
extern "C" void kernel_launch(void* const* d_in, const int* in_sizes, int n_in,
                              void* d_out, int out_size, void* d_ws, size_t ws_size,
                              hipStream_t stream) {
  const float* q = (const float*)d_in[0];
  const float* kv = (const float*)d_in[1];
  const float* Wq = (const float*)d_in[2];
  const float* Wkv = (const float*)d_in[3];
  const float* Wfc = (const float*)d_in[4];
  float* out = (float*)d_out;
  char* ws = (char*)d_ws;

  u16* q_bf  = (u16*)(ws + 0);            // 67108864  (also reused as o_buf)
  u16* kv_bf = (u16*)(ws + 67108864);     // 67108864
  u16* qp    = (u16*)(ws + 134217728);    // 67108864
  u16* kvp   = (u16*)(ws + 201326592);    // 134217728
  u16* Wq_t  = (u16*)(ws + 335544320);    // 524288
  u16* Wkv_t = (u16*)(ws + 336068608);    // 1048576
  u16* Wfc_t = (u16*)(ws + 337117184);    // 524288
  u16* o_buf = q_bf;

  prep_kernel<<<4352, 256, 0, stream>>>(q, kv, Wq, Wkv, Wfc, q_bf, kv_bf, Wq_t, Wkv_t, Wfc_t);

  gemm256<false><<<(MM / 256) * (CC / 256), 512, 0, stream>>>(q_bf, Wq_t, qp, MM, CC, CC);
  gemm256<false><<<(MM / 256) * (2 * CC / 256), 512, 0, stream>>>(kv_bf, Wkv_t, kvp, MM, 2 * CC, CC);

  attn_kernel<<<BB * 64 * 8, 512, 0, stream>>>(qp, kvp, o_buf);

  gemm256<true><<<(MM / 256) * (CC / 256), 512, 0, stream>>>(o_buf, Wfc_t, out, MM, CC, CC);
}